// Round 1
// baseline (717.414 us; speedup 1.0000x reference)
//
#include <hip/hip_runtime.h>

// SphericalConvMHF — fp32 pipeline, round 1 (correctness-first).
//
// Stages (all on `stream`, workspace layout in floats):
//   K0 k_tables : T (fwd DFT, 256x256), Ti (inv DFT incl. irfft weights),
//                 P[m][l][k] (orthonormal assoc. Legendre, fp64 recurrence),
//                 PW = P * Clenshaw-Curtis weights. l<m rows zero-filled.
//   K1 gemm_nt  : XH[mc][bc*256+k] = sum_n T[mc][n] * x[bc,k,n]   (rfft as GEMM)
//   K2 gemm_nt  : spec[mc][l][bc]  = sum_k PW[m][l][k] * XH[mc][bc][k]
//   K3 k_stagec : out[mc][l][bo]   = sum_i spec[mc][l][b*32+i] * w[i][o][x(l,m,p)]
//   K4 gemm_tn  : XM[mc][bo*256+k] = sum_l out[mc][l][bo] * P[m][l][k]
//   K5 gemm_tn  : y[bo,k,n]        = sum_mc XM[mc][bo*256+k] * Ti[mc][n] (irfft*N)
//
// m=128 plane (P==0) dropped end-to-end; l<m entries never contribute
// (P rows zero; poisoned ws reads multiply by exact 0.0f -> finite, exact).
// Workspace: 42,074,112 floats = ~168.3 MB.

#define TILE 128
#define BK 16

// ---------------- K0: table generation (fp64, matches numpy) ----------------
__global__ __launch_bounds__(256) void k_tables(float* __restrict__ T,
                                                float* __restrict__ Ti,
                                                float* __restrict__ P,
                                                float* __restrict__ PW) {
  const double PI = 3.14159265358979323846264338327950288;
  const int t = threadIdx.x;
  const int m = blockIdx.x;
  if (m == 128) {
    // trig tables: row mc = 2*mm+p, col n
    const int n = t;
    const double scale = 2.0 * PI / 256.0;
    for (int mm = 0; mm < 128; ++mm) {
      const int r = (mm * n) & 255;            // exact angle reduction
      const double ang = scale * (double)r;
      const double c = cos(ang), s = sin(ang);
      const double wm = (mm == 0) ? 1.0 : 2.0; // irfft real-expansion weight
      T [(2 * mm) * 256 + n]     = (float)( scale * c);
      T [(2 * mm + 1) * 256 + n] = (float)(-scale * s);
      Ti[(2 * mm) * 256 + n]     = (float)( wm * c);
      Ti[(2 * mm + 1) * 256 + n] = (float)(-wm * s);
    }
    return;
  }
  const int k = t;  // latitude index
  const double tj = PI * (double)k / 255.0;
  // Clenshaw-Curtis weight for this node
  double ssum = 0.0;
  for (int kk = 1; kk <= 127; ++kk)
    ssum += 2.0 / (4.0 * (double)kk * kk - 1.0) * cos(2.0 * tj * (double)kk);
  const double cj = (k == 0 || k == 255) ? 1.0 : 2.0;
  const double wq = cj / 255.0 * (1.0 - ssum);
  const double ct = cos(tj), st = sin(tj);
  // diagonal P[m][m] via running product
  double pmm = 1.0 / sqrt(4.0 * PI);
  for (int mm = 1; mm <= m; ++mm)
    pmm = pmm * (-sqrt((2.0 * mm + 1.0) / (2.0 * mm)) * st);
  float* Pm  = P  + (size_t)m * 128 * 256;
  float* PWm = PW + (size_t)m * 128 * 256;
  for (int l = 0; l < m; ++l) { Pm[l * 256 + k] = 0.f; PWm[l * 256 + k] = 0.f; }
  Pm [m * 256 + k] = (float)pmm;
  PWm[m * 256 + k] = (float)(pmm * wq);
  if (m + 1 < 128) {
    double pl2 = pmm;
    double pl1 = sqrt(2.0 * m + 3.0) * ct * pmm;
    Pm [(m + 1) * 256 + k] = (float)pl1;
    PWm[(m + 1) * 256 + k] = (float)(pl1 * wq);
    for (int l = m + 2; l < 128; ++l) {
      const double dl = (double)l, dm = (double)m;
      const double a = sqrt((4.0 * dl * dl - 1.0) / (dl * dl - dm * dm));
      const double b = sqrt(((dl - 1.0) * (dl - 1.0) - dm * dm) /
                            (4.0 * (dl - 1.0) * (dl - 1.0) - 1.0));
      const double pl = a * (ct * pl1 - b * pl2);
      Pm [l * 256 + k] = (float)pl;
      PWm[l * 256 + k] = (float)(pl * wq);
      pl2 = pl1; pl1 = pl;
    }
  }
}

// ---------------- fp32 tiled GEMMs (128x128 tile, 8x8 microtile) ----------------
// NT: C[i][j] = sum_k A[i*lda+k] * B[j*ldb+k]
__global__ __launch_bounds__(256) void gemm_nt(
    const float* __restrict__ A, const float* __restrict__ B, float* __restrict__ C,
    int K, int lda, int ldb, int ldc,
    long aZ, long bZ, long cZ, int aShift, int bShift)
{
  __shared__ float As[BK][TILE + 4];
  __shared__ float Bs[BK][TILE + 4];
  const int z = blockIdx.z;
  A += ((long)(z >> aShift)) * aZ;
  B += ((long)(z >> bShift)) * bZ;
  C += (long)z * cZ;
  const int i0 = blockIdx.y * TILE;
  const int j0 = blockIdx.x * TILE;
  const int tid = threadIdx.x;
  const int tx = tid & 15, ty = tid >> 4;
  const int r = tid >> 1;            // tile row 0..127
  const int c4 = (tid & 1) * 8;      // k offset 0 or 8
  float acc[8][8] = {{0.f}};
  for (int k0 = 0; k0 < K; k0 += BK) {
    float4 av0 = *(const float4*)&A[(long)(i0 + r) * lda + k0 + c4];
    float4 av1 = *(const float4*)&A[(long)(i0 + r) * lda + k0 + c4 + 4];
    float4 bv0 = *(const float4*)&B[(long)(j0 + r) * ldb + k0 + c4];
    float4 bv1 = *(const float4*)&B[(long)(j0 + r) * ldb + k0 + c4 + 4];
    __syncthreads();
    As[c4 + 0][r] = av0.x; As[c4 + 1][r] = av0.y; As[c4 + 2][r] = av0.z; As[c4 + 3][r] = av0.w;
    As[c4 + 4][r] = av1.x; As[c4 + 5][r] = av1.y; As[c4 + 6][r] = av1.z; As[c4 + 7][r] = av1.w;
    Bs[c4 + 0][r] = bv0.x; Bs[c4 + 1][r] = bv0.y; Bs[c4 + 2][r] = bv0.z; Bs[c4 + 3][r] = bv0.w;
    Bs[c4 + 4][r] = bv1.x; Bs[c4 + 5][r] = bv1.y; Bs[c4 + 6][r] = bv1.z; Bs[c4 + 7][r] = bv1.w;
    __syncthreads();
#pragma unroll
    for (int kk = 0; kk < BK; ++kk) {
      float a[8], b[8];
      *(float4*)&a[0] = *(const float4*)&As[kk][ty * 8];
      *(float4*)&a[4] = *(const float4*)&As[kk][ty * 8 + 4];
      *(float4*)&b[0] = *(const float4*)&Bs[kk][tx * 8];
      *(float4*)&b[4] = *(const float4*)&Bs[kk][tx * 8 + 4];
#pragma unroll
      for (int ii = 0; ii < 8; ++ii)
#pragma unroll
        for (int jj = 0; jj < 8; ++jj)
          acc[ii][jj] = fmaf(a[ii], b[jj], acc[ii][jj]);
    }
  }
#pragma unroll
  for (int ii = 0; ii < 8; ++ii) {
    float4 o0 = make_float4(acc[ii][0], acc[ii][1], acc[ii][2], acc[ii][3]);
    float4 o1 = make_float4(acc[ii][4], acc[ii][5], acc[ii][6], acc[ii][7]);
    long cb = (long)(i0 + ty * 8 + ii) * ldc + j0 + tx * 8;
    *(float4*)&C[cb] = o0;
    *(float4*)&C[cb + 4] = o1;
  }
}

// TN: C[i][j] = sum_k A[k*lda+i] * B[k*ldb+j]   (kFromZ: skip l < (m & ~15))
__global__ __launch_bounds__(256) void gemm_tn(
    const float* __restrict__ A, const float* __restrict__ B, float* __restrict__ C,
    int K, int lda, int ldb, int ldc,
    long aZ, long bZ, long cZ, int aShift, int bShift, int kFromZ)
{
  __shared__ float As[BK][TILE + 4];
  __shared__ float Bs[BK][TILE + 4];
  const int z = blockIdx.z;
  A += ((long)(z >> aShift)) * aZ;
  B += ((long)(z >> bShift)) * bZ;
  C += (long)z * cZ;
  const int i0 = blockIdx.y * TILE;
  const int j0 = blockIdx.x * TILE;
  const int tid = threadIdx.x;
  const int tx = tid & 15, ty = tid >> 4;
  const int kr = tid >> 4;           // k row within chunk 0..15
  const int ic = (tid & 15) * 8;     // column offset 0..120
  const int kstart = kFromZ ? ((z >> 1) & ~(BK - 1)) : 0;
  float acc[8][8] = {{0.f}};
  for (int k0 = kstart; k0 < K; k0 += BK) {
    float4 av0 = *(const float4*)&A[(long)(k0 + kr) * lda + i0 + ic];
    float4 av1 = *(const float4*)&A[(long)(k0 + kr) * lda + i0 + ic + 4];
    float4 bv0 = *(const float4*)&B[(long)(k0 + kr) * ldb + j0 + ic];
    float4 bv1 = *(const float4*)&B[(long)(k0 + kr) * ldb + j0 + ic + 4];
    __syncthreads();
    *(float4*)&As[kr][ic] = av0; *(float4*)&As[kr][ic + 4] = av1;
    *(float4*)&Bs[kr][ic] = bv0; *(float4*)&Bs[kr][ic + 4] = bv1;
    __syncthreads();
#pragma unroll
    for (int kk = 0; kk < BK; ++kk) {
      float a[8], b[8];
      *(float4*)&a[0] = *(const float4*)&As[kk][ty * 8];
      *(float4*)&a[4] = *(const float4*)&As[kk][ty * 8 + 4];
      *(float4*)&b[0] = *(const float4*)&Bs[kk][tx * 8];
      *(float4*)&b[4] = *(const float4*)&Bs[kk][tx * 8 + 4];
#pragma unroll
      for (int ii = 0; ii < 8; ++ii)
#pragma unroll
        for (int jj = 0; jj < 8; ++jj)
          acc[ii][jj] = fmaf(a[ii], b[jj], acc[ii][jj]);
    }
  }
#pragma unroll
  for (int ii = 0; ii < 8; ++ii) {
    float4 o0 = make_float4(acc[ii][0], acc[ii][1], acc[ii][2], acc[ii][3]);
    float4 o1 = make_float4(acc[ii][4], acc[ii][5], acc[ii][6], acc[ii][7]);
    long cb = (long)(i0 + ty * 8 + ii) * ldc + j0 + tx * 8;
    *(float4*)&C[cb] = o0;
    *(float4*)&C[cb + 4] = o1;
  }
}

// ---------------- K3: per-coefficient channel mixing ----------------
// block (m=bx, l=by), m<=l; thread t=(b,o); out[b,o] = sum_i spec[b,i]*w[i,o,x]
__global__ __launch_bounds__(256) void k_stagec(const float* __restrict__ spec,
                                                const float* __restrict__ w,
                                                float* __restrict__ outb) {
  const int m = blockIdx.x, l = blockIdx.y;
  if (m > l) return;
  __shared__ float s_re[256];
  __shared__ float s_im[256];
  const int t = threadIdx.x;
  const int pr = (2 * m) * 32768 + l * 256;
  const int pi = pr + 32768;
  s_re[t] = spec[pr + t];
  s_im[t] = spec[pi + t];
  __syncthreads();
  const int b = t >> 5, o = t & 31;
  const long x2 = (long)(l * 129 + m) * 2;
  float ar = 0.f, ai = 0.f;
#pragma unroll
  for (int i = 0; i < 32; ++i) {
    const float2 wv = *(const float2*)&w[(long)(i * 32 + o) * 33024 + x2];
    ar = fmaf(s_re[b * 32 + i], wv.x, ar);
    ai = fmaf(s_im[b * 32 + i], wv.y, ai);
  }
  outb[pr + t] = ar;
  outb[pi + t] = ai;
}

// ---------------- launch ----------------
extern "C" void kernel_launch(void* const* d_in, const int* in_sizes, int n_in,
                              void* d_out, int out_size, void* d_ws, size_t ws_size,
                              hipStream_t stream) {
  const float* x = (const float*)d_in[0];   // (8,32,256,256)
  const float* w = (const float*)d_in[1];   // (32,32,33024)
  float* y = (float*)d_out;                 // (8,32,256,256)
  float* ws = (float*)d_ws;

  float* T    = ws;                  //  65,536  fwd DFT table
  float* Ti   = T + 65536;           //  65,536  inv DFT table
  float* P    = Ti + 65536;          //  4,194,304  Legendre
  float* PW   = P + 4194304;         //  4,194,304  Legendre * quad weights
  float* spec = PW + 4194304;        //  8,388,608  [mc][l][bc]
  float* outb = spec + 8388608;      //  8,388,608  [mc][l][bo]
  float* XH   = outb + 8388608;      // 16,777,216  [mc][bc*256+k]; reused as XM
  float* XM   = XH;                  // total 42,074,112 floats (~168.3 MB)

  // K0: tables (blocks 0..127: Legendre per m; block 128: trig tables)
  k_tables<<<dim3(129), dim3(256), 0, stream>>>(T, Ti, P, PW);

  // K1: forward DFT   XH[mc][row] = sum_n T[mc][n]*x[row][n]; M=256,N=65536,K=256
  gemm_nt<<<dim3(512, 2, 1), dim3(256), 0, stream>>>(
      T, x, XH, 256, 256, 256, 65536, 0, 0, 0, 0, 0);

  // K2: forward Legendre; per z=mc: spec[l][bc] = sum_k PW[m][l][k]*XH[z][bc][k]
  gemm_nt<<<dim3(2, 1, 256), dim3(256), 0, stream>>>(
      PW, XH, spec, 256, 256, 256, 256, 32768L, 65536L, 32768L, 1, 0);

  // K3: channel mixing against weight
  k_stagec<<<dim3(128, 128), dim3(256), 0, stream>>>(spec, w, outb);

  // K4: inverse Legendre; per z=mc: XM[z][bo*256+k] = sum_l outb[z][l][bo]*P[m][l][k]
  gemm_tn<<<dim3(2, 2, 256), dim3(256), 0, stream>>>(
      outb, P, XM, 128, 256, 256, 256, 32768L, 32768L, 65536L, 0, 1, 1);

  // K5: inverse DFT (irfft*N): y[row][n] = sum_mc XM[mc][row]*Ti[mc][n]
  gemm_tn<<<dim3(2, 512, 1), dim3(256), 0, stream>>>(
      XM, Ti, y, 256, 65536, 256, 256, 0, 0, 0, 0, 0, 0);
}

// Round 2
// 585.518 us; speedup vs baseline: 1.2253x; 1.2253x over previous
//
#include <hip/hip_runtime.h>

// SphericalConvMHF — fp32 pipeline, round 2: coalesced stage-C.
//
// Stages (all on `stream`, workspace layout in floats):
//   K0 k_tables : T (fwd DFT, 256x256), Ti (inv DFT incl. irfft weights),
//                 P[m][l][k] (orthonormal assoc. Legendre, fp64 recurrence),
//                 PW = P * Clenshaw-Curtis weights. l<m rows zero-filled.
//   K1 gemm_nt  : XH[mc][bc*256+k] = sum_n T[mc][n] * x[bc,k,n]   (rfft as GEMM)
//   K2 gemm_nt  : spec[mc][l][bc]  = sum_k PW[m][l][k] * XH[mc][bc][k]
//   K3 k_stagec : out[mc][l][bo]   = sum_i spec[mc][l][b*32+i] * w[i][o][x(l,m,p)]
//                 (coalesced along x; one l x 32-coeff chunk per block)
//   K4 gemm_tn  : XM[mc][bo*256+k] = sum_l out[mc][l][bo] * P[m][l][k]
//   K5 gemm_tn  : y[bo,k,n]        = sum_mc XM[mc][bo*256+k] * Ti[mc][n] (irfft*N)
//
// m=128 plane (P==0) dropped end-to-end; l<m entries never contribute
// (P rows zero; poisoned ws reads multiply by exact 0.0f -> finite, exact).
// Workspace: 42,074,112 floats = ~168.3 MB.

#define TILE 128
#define BK 16

// ---------------- K0: table generation (fp64, matches numpy) ----------------
__global__ __launch_bounds__(256) void k_tables(float* __restrict__ T,
                                                float* __restrict__ Ti,
                                                float* __restrict__ P,
                                                float* __restrict__ PW) {
  const double PI = 3.14159265358979323846264338327950288;
  const int t = threadIdx.x;
  const int m = blockIdx.x;
  if (m == 128) {
    // trig tables: row mc = 2*mm+p, col n
    const int n = t;
    const double scale = 2.0 * PI / 256.0;
    for (int mm = 0; mm < 128; ++mm) {
      const int r = (mm * n) & 255;            // exact angle reduction
      const double ang = scale * (double)r;
      const double c = cos(ang), s = sin(ang);
      const double wm = (mm == 0) ? 1.0 : 2.0; // irfft real-expansion weight
      T [(2 * mm) * 256 + n]     = (float)( scale * c);
      T [(2 * mm + 1) * 256 + n] = (float)(-scale * s);
      Ti[(2 * mm) * 256 + n]     = (float)( wm * c);
      Ti[(2 * mm + 1) * 256 + n] = (float)(-wm * s);
    }
    return;
  }
  const int k = t;  // latitude index
  const double tj = PI * (double)k / 255.0;
  // Clenshaw-Curtis weight for this node
  double ssum = 0.0;
  for (int kk = 1; kk <= 127; ++kk)
    ssum += 2.0 / (4.0 * (double)kk * kk - 1.0) * cos(2.0 * tj * (double)kk);
  const double cj = (k == 0 || k == 255) ? 1.0 : 2.0;
  const double wq = cj / 255.0 * (1.0 - ssum);
  const double ct = cos(tj), st = sin(tj);
  // diagonal P[m][m] via running product
  double pmm = 1.0 / sqrt(4.0 * PI);
  for (int mm = 1; mm <= m; ++mm)
    pmm = pmm * (-sqrt((2.0 * mm + 1.0) / (2.0 * mm)) * st);
  float* Pm  = P  + (size_t)m * 128 * 256;
  float* PWm = PW + (size_t)m * 128 * 256;
  for (int l = 0; l < m; ++l) { Pm[l * 256 + k] = 0.f; PWm[l * 256 + k] = 0.f; }
  Pm [m * 256 + k] = (float)pmm;
  PWm[m * 256 + k] = (float)(pmm * wq);
  if (m + 1 < 128) {
    double pl2 = pmm;
    double pl1 = sqrt(2.0 * m + 3.0) * ct * pmm;
    Pm [(m + 1) * 256 + k] = (float)pl1;
    PWm[(m + 1) * 256 + k] = (float)(pl1 * wq);
    for (int l = m + 2; l < 128; ++l) {
      const double dl = (double)l, dm = (double)m;
      const double a = sqrt((4.0 * dl * dl - 1.0) / (dl * dl - dm * dm));
      const double b = sqrt(((dl - 1.0) * (dl - 1.0) - dm * dm) /
                            (4.0 * (dl - 1.0) * (dl - 1.0) - 1.0));
      const double pl = a * (ct * pl1 - b * pl2);
      Pm [l * 256 + k] = (float)pl;
      PWm[l * 256 + k] = (float)(pl * wq);
      pl2 = pl1; pl1 = pl;
    }
  }
}

// ---------------- fp32 tiled GEMMs (128x128 tile, 8x8 microtile) ----------------
// NT: C[i][j] = sum_k A[i*lda+k] * B[j*ldb+k]
__global__ __launch_bounds__(256) void gemm_nt(
    const float* __restrict__ A, const float* __restrict__ B, float* __restrict__ C,
    int K, int lda, int ldb, int ldc,
    long aZ, long bZ, long cZ, int aShift, int bShift)
{
  __shared__ float As[BK][TILE + 4];
  __shared__ float Bs[BK][TILE + 4];
  const int z = blockIdx.z;
  A += ((long)(z >> aShift)) * aZ;
  B += ((long)(z >> bShift)) * bZ;
  C += (long)z * cZ;
  const int i0 = blockIdx.y * TILE;
  const int j0 = blockIdx.x * TILE;
  const int tid = threadIdx.x;
  const int tx = tid & 15, ty = tid >> 4;
  const int r = tid >> 1;            // tile row 0..127
  const int c4 = (tid & 1) * 8;      // k offset 0 or 8
  float acc[8][8] = {{0.f}};
  for (int k0 = 0; k0 < K; k0 += BK) {
    float4 av0 = *(const float4*)&A[(long)(i0 + r) * lda + k0 + c4];
    float4 av1 = *(const float4*)&A[(long)(i0 + r) * lda + k0 + c4 + 4];
    float4 bv0 = *(const float4*)&B[(long)(j0 + r) * ldb + k0 + c4];
    float4 bv1 = *(const float4*)&B[(long)(j0 + r) * ldb + k0 + c4 + 4];
    __syncthreads();
    As[c4 + 0][r] = av0.x; As[c4 + 1][r] = av0.y; As[c4 + 2][r] = av0.z; As[c4 + 3][r] = av0.w;
    As[c4 + 4][r] = av1.x; As[c4 + 5][r] = av1.y; As[c4 + 6][r] = av1.z; As[c4 + 7][r] = av1.w;
    Bs[c4 + 0][r] = bv0.x; Bs[c4 + 1][r] = bv0.y; Bs[c4 + 2][r] = bv0.z; Bs[c4 + 3][r] = bv0.w;
    Bs[c4 + 4][r] = bv1.x; Bs[c4 + 5][r] = bv1.y; Bs[c4 + 6][r] = bv1.z; Bs[c4 + 7][r] = bv1.w;
    __syncthreads();
#pragma unroll
    for (int kk = 0; kk < BK; ++kk) {
      float a[8], b[8];
      *(float4*)&a[0] = *(const float4*)&As[kk][ty * 8];
      *(float4*)&a[4] = *(const float4*)&As[kk][ty * 8 + 4];
      *(float4*)&b[0] = *(const float4*)&Bs[kk][tx * 8];
      *(float4*)&b[4] = *(const float4*)&Bs[kk][tx * 8 + 4];
#pragma unroll
      for (int ii = 0; ii < 8; ++ii)
#pragma unroll
        for (int jj = 0; jj < 8; ++jj)
          acc[ii][jj] = fmaf(a[ii], b[jj], acc[ii][jj]);
    }
  }
#pragma unroll
  for (int ii = 0; ii < 8; ++ii) {
    float4 o0 = make_float4(acc[ii][0], acc[ii][1], acc[ii][2], acc[ii][3]);
    float4 o1 = make_float4(acc[ii][4], acc[ii][5], acc[ii][6], acc[ii][7]);
    long cb = (long)(i0 + ty * 8 + ii) * ldc + j0 + tx * 8;
    *(float4*)&C[cb] = o0;
    *(float4*)&C[cb + 4] = o1;
  }
}

// TN: C[i][j] = sum_k A[k*lda+i] * B[k*ldb+j]   (kFromZ: skip l < (m & ~15))
__global__ __launch_bounds__(256) void gemm_tn(
    const float* __restrict__ A, const float* __restrict__ B, float* __restrict__ C,
    int K, int lda, int ldb, int ldc,
    long aZ, long bZ, long cZ, int aShift, int bShift, int kFromZ)
{
  __shared__ float As[BK][TILE + 4];
  __shared__ float Bs[BK][TILE + 4];
  const int z = blockIdx.z;
  A += ((long)(z >> aShift)) * aZ;
  B += ((long)(z >> bShift)) * bZ;
  C += (long)z * cZ;
  const int i0 = blockIdx.y * TILE;
  const int j0 = blockIdx.x * TILE;
  const int tid = threadIdx.x;
  const int tx = tid & 15, ty = tid >> 4;
  const int kr = tid >> 4;           // k row within chunk 0..15
  const int ic = (tid & 15) * 8;     // column offset 0..120
  const int kstart = kFromZ ? ((z >> 1) & ~(BK - 1)) : 0;
  float acc[8][8] = {{0.f}};
  for (int k0 = kstart; k0 < K; k0 += BK) {
    float4 av0 = *(const float4*)&A[(long)(k0 + kr) * lda + i0 + ic];
    float4 av1 = *(const float4*)&A[(long)(k0 + kr) * lda + i0 + ic + 4];
    float4 bv0 = *(const float4*)&B[(long)(k0 + kr) * ldb + j0 + ic];
    float4 bv1 = *(const float4*)&B[(long)(k0 + kr) * ldb + j0 + ic + 4];
    __syncthreads();
    *(float4*)&As[kr][ic] = av0; *(float4*)&As[kr][ic + 4] = av1;
    *(float4*)&Bs[kr][ic] = bv0; *(float4*)&Bs[kr][ic + 4] = bv1;
    __syncthreads();
#pragma unroll
    for (int kk = 0; kk < BK; ++kk) {
      float a[8], b[8];
      *(float4*)&a[0] = *(const float4*)&As[kk][ty * 8];
      *(float4*)&a[4] = *(const float4*)&As[kk][ty * 8 + 4];
      *(float4*)&b[0] = *(const float4*)&Bs[kk][tx * 8];
      *(float4*)&b[4] = *(const float4*)&Bs[kk][tx * 8 + 4];
#pragma unroll
      for (int ii = 0; ii < 8; ++ii)
#pragma unroll
        for (int jj = 0; jj < 8; ++jj)
          acc[ii][jj] = fmaf(a[ii], b[jj], acc[ii][jj]);
    }
  }
#pragma unroll
  for (int ii = 0; ii < 8; ++ii) {
    float4 o0 = make_float4(acc[ii][0], acc[ii][1], acc[ii][2], acc[ii][3]);
    float4 o1 = make_float4(acc[ii][4], acc[ii][5], acc[ii][6], acc[ii][7]);
    long cb = (long)(i0 + ty * 8 + ii) * ldc + j0 + tx * 8;
    *(float4*)&C[cb] = o0;
    *(float4*)&C[cb + 4] = o1;
  }
}

// ---------------- K3: per-coefficient channel mixing (coalesced) ----------------
// block (cb=x-chunk, l=y); coefficients cc = cb*32..cb*32+31, mc-plane = cc.
// x(l,cc) = 258*l + cc in the weight's coefficient axis (contiguous).
// out[cc][l][b*32+o] = sum_i spec[cc][l][b*32+i] * w[(i*32+o)][x0+cc']
// Weight staged via LDS in 4 i-subchunks (8 i's x 32 o's = 256 rows each);
// spec chunk staged once; output round-trips LDS for coalesced stores.
__global__ __launch_bounds__(256) void k_stagec(const float* __restrict__ spec,
                                                const float* __restrict__ w,
                                                float* __restrict__ outb) {
  const int cb = blockIdx.x, l = blockIdx.y;
  if (cb * 16 > l) return;               // chunk entirely past m=l
  __shared__ float s_spec[32 * 257];     // [cc][b*32+i], pad 257
  __shared__ float s_w[256 * 33];        // [rho][cc], pad 33; reused as s_out[cc][257]
  const int t = threadIdx.x;
  const int c = t & 31, og = t >> 5;     // compute map: coeff c, o-group og (4 o's)
  const size_t x0 = 258u * l + cb * 32;
  // stage spec chunk: 32 coalesced 1KB loads
  for (int cc = 0; cc < 32; ++cc)
    s_spec[cc * 257 + t] = spec[(size_t)(cb * 32 + cc) * 32768 + l * 256 + t];
  float acc[8][4] = {{0.f}};
  const int lr = t >> 4;                 // staging: row-in-pass 0..15
  const int lq = (t & 15) * 2;           // staging: coeff pair 0,2,..,30
  for (int isub = 0; isub < 4; ++isub) {
    __syncthreads();                     // spec visible (isub 0); s_w reuse (isub>0)
    // stage weight rows rho = pass*16+lr: i = isub*8 + rho>>5, o = rho&31
    for (int pass = 0; pass < 16; ++pass) {
      const int rho = pass * 16 + lr;
      const int io = (isub * 8 + (rho >> 5)) * 32 + (rho & 31);
      const float2 wv = *(const float2*)&w[(size_t)io * 33024 + x0 + lq];
      s_w[rho * 33 + lq]     = wv.x;
      s_w[rho * 33 + lq + 1] = wv.y;
    }
    __syncthreads();
    // compute: acc[b][od] += spec[b][i][c] * w[i][og*4+od][c]
#pragma unroll
    for (int idp = 0; idp < 4; ++idp) {
      const int i0 = isub * 8 + idp * 2; // absolute i (even)
      const int r0 = idp * 64;           // local rho base for i0
      float2 sv[8];
#pragma unroll
      for (int b = 0; b < 8; ++b)
        sv[b] = *(const float2*)&s_spec[c * 257 + b * 32 + i0];
      float wv0[4], wv1[4];
#pragma unroll
      for (int od = 0; od < 4; ++od) {
        wv0[od] = s_w[(r0 + og * 4 + od) * 33 + c];
        wv1[od] = s_w[(r0 + 32 + og * 4 + od) * 33 + c];
      }
#pragma unroll
      for (int b = 0; b < 8; ++b)
#pragma unroll
        for (int od = 0; od < 4; ++od)
          acc[b][od] = fmaf(sv[b].x, wv0[od], fmaf(sv[b].y, wv1[od], acc[b][od]));
    }
  }
  // write out through LDS for coalesced stores (reuse s_w as s_out[cc][257])
  __syncthreads();
#pragma unroll
  for (int b = 0; b < 8; ++b)
#pragma unroll
    for (int od = 0; od < 4; ++od)
      s_w[c * 257 + b * 32 + og * 4 + od] = acc[b][od];
  __syncthreads();
  for (int cc = 0; cc < 32; ++cc)
    outb[(size_t)(cb * 32 + cc) * 32768 + l * 256 + t] = s_w[cc * 257 + t];
}

// ---------------- launch ----------------
extern "C" void kernel_launch(void* const* d_in, const int* in_sizes, int n_in,
                              void* d_out, int out_size, void* d_ws, size_t ws_size,
                              hipStream_t stream) {
  const float* x = (const float*)d_in[0];   // (8,32,256,256)
  const float* w = (const float*)d_in[1];   // (32,32,33024)
  float* y = (float*)d_out;                 // (8,32,256,256)
  float* ws = (float*)d_ws;

  float* T    = ws;                  //  65,536  fwd DFT table
  float* Ti   = T + 65536;           //  65,536  inv DFT table
  float* P    = Ti + 65536;          //  4,194,304  Legendre
  float* PW   = P + 4194304;         //  4,194,304  Legendre * quad weights
  float* spec = PW + 4194304;        //  8,388,608  [mc][l][bc]
  float* outb = spec + 8388608;      //  8,388,608  [mc][l][bo]
  float* XH   = outb + 8388608;      // 16,777,216  [mc][bc*256+k]; reused as XM
  float* XM   = XH;                  // total 42,074,112 floats (~168.3 MB)

  // K0: tables (blocks 0..127: Legendre per m; block 128: trig tables)
  k_tables<<<dim3(129), dim3(256), 0, stream>>>(T, Ti, P, PW);

  // K1: forward DFT   XH[mc][row] = sum_n T[mc][n]*x[row][n]; M=256,N=65536,K=256
  gemm_nt<<<dim3(512, 2, 1), dim3(256), 0, stream>>>(
      T, x, XH, 256, 256, 256, 65536, 0, 0, 0, 0, 0);

  // K2: forward Legendre; per z=mc: spec[l][bc] = sum_k PW[m][l][k]*XH[z][bc][k]
  gemm_nt<<<dim3(2, 1, 256), dim3(256), 0, stream>>>(
      PW, XH, spec, 256, 256, 256, 256, 32768L, 65536L, 32768L, 1, 0);

  // K3: channel mixing against weight (coalesced along coefficient axis)
  k_stagec<<<dim3(8, 128), dim3(256), 0, stream>>>(spec, w, outb);

  // K4: inverse Legendre; per z=mc: XM[z][bo*256+k] = sum_l outb[z][l][bo]*P[m][l][k]
  gemm_tn<<<dim3(2, 2, 256), dim3(256), 0, stream>>>(
      outb, P, XM, 128, 256, 256, 256, 32768L, 32768L, 65536L, 0, 1, 1);

  // K5: inverse DFT (irfft*N): y[row][n] = sum_mc XM[mc][row]*Ti[mc][n]
  gemm_tn<<<dim3(2, 512, 1), dim3(256), 0, stream>>>(
      XM, Ti, y, 256, 65536, 256, 256, 0, 0, 0, 0, 0, 0);
}

// Round 3
// 498.720 us; speedup vs baseline: 1.4385x; 1.1740x over previous
//
#include <hip/hip_runtime.h>

// SphericalConvMHF — round 3: split-bf16 MFMA for all four GEMM stages.
// Pipeline: K0 tables(hi/lo bf16) -> K1 fwd-DFT (MFMA, x cvt in-kernel)
//   -> K2 fwd-Legendre (MFMA) -> K3 channel-mix (fp32, unchanged)
//   -> K4 inv-Legendre (MFMA, outb transpose+cvt) -> K5 inv-DFT (MFMA, XM transpose+cvt).
// Split: v = hi + lo (bf16 RTN); C = Ah*Bh + Ah*Bl + Al*Bh (drop lo*lo, ~2^-18 rel).
// XH computed in 2 batch-halves so workspace = 168,296,448 B (same as R2).
// Poison safety: unwritten outb planes (m>l chunks) are finite and multiply PT==0.

typedef __attribute__((ext_vector_type(8))) short short8;
typedef __attribute__((ext_vector_type(4))) float f32x4;

__device__ __forceinline__ ushort bf16_rtn(float v) {
  uint u = __float_as_uint(v);
  return (ushort)((u + 0x7FFFu + ((u >> 16) & 1u)) >> 16);
}
__device__ __forceinline__ void split2(float v, ushort& h, ushort& l) {
  h = bf16_rtn(v);
  float hf = __uint_as_float(((uint)h) << 16);
  l = bf16_rtn(v - hf);
}

// ---------------- K0: table generation (fp64 recurrence, split bf16 out) ----
__global__ __launch_bounds__(256) void k_tables(
    ushort* __restrict__ Th, ushort* __restrict__ Tl,
    ushort* __restrict__ TiTh, ushort* __restrict__ TiTl,
    ushort* __restrict__ PWh, ushort* __restrict__ PWl,
    ushort* __restrict__ PTh, ushort* __restrict__ PTl) {
  const double PI = 3.14159265358979323846264338327950288;
  const int t = threadIdx.x;
  const int m = blockIdx.x;
  if (m == 128) {             // trig tables: T[mc][n] and TiT[n][mc]
    const int n = t;
    const double scale = 2.0 * PI / 256.0;
    for (int mm = 0; mm < 128; ++mm) {
      const int r = (mm * n) & 255;
      const double ang = scale * (double)r;
      const double c = cos(ang), s = sin(ang);
      const double wm = (mm == 0) ? 1.0 : 2.0;
      ushort h, l;
      split2((float)(scale * c), h, l);  Th[(2*mm)*256+n]=h;   Tl[(2*mm)*256+n]=l;
      split2((float)(-scale * s), h, l); Th[(2*mm+1)*256+n]=h; Tl[(2*mm+1)*256+n]=l;
      split2((float)(wm * c), h, l);     TiTh[n*256+2*mm]=h;   TiTl[n*256+2*mm]=l;
      split2((float)(-wm * s), h, l);    TiTh[n*256+2*mm+1]=h; TiTl[n*256+2*mm+1]=l;
    }
    return;
  }
  const int k = t;  // latitude index
  const double tj = PI * (double)k / 255.0;
  double ssum = 0.0;
  for (int kk = 1; kk <= 127; ++kk)
    ssum += 2.0 / (4.0 * (double)kk * kk - 1.0) * cos(2.0 * tj * (double)kk);
  const double cj = (k == 0 || k == 255) ? 1.0 : 2.0;
  const double wq = cj / 255.0 * (1.0 - ssum);
  const double ct = cos(tj), st = sin(tj);
  double pmm = 1.0 / sqrt(4.0 * PI);
  for (int mm = 1; mm <= m; ++mm)
    pmm = pmm * (-sqrt((2.0 * mm + 1.0) / (2.0 * mm)) * st);
  const size_t pwB = (size_t)m * 32768;                 // [l][k], k = t
  const size_t ptB = (size_t)m * 32768 + (size_t)k * 128; // [k][l]
  ushort h, l2;
  for (int l = 0; l < m; ++l) {
    PWh[pwB + l*256 + k] = 0; PWl[pwB + l*256 + k] = 0;
    PTh[ptB + l] = 0;         PTl[ptB + l] = 0;
  }
  split2((float)pmm, h, l2);        PTh[ptB + m] = h; PTl[ptB + m] = l2;
  split2((float)(pmm*wq), h, l2);   PWh[pwB + m*256 + k] = h; PWl[pwB + m*256 + k] = l2;
  if (m + 1 < 128) {
    double pl2v = pmm;
    double pl1 = sqrt(2.0 * m + 3.0) * ct * pmm;
    split2((float)pl1, h, l2);      PTh[ptB + m+1] = h; PTl[ptB + m+1] = l2;
    split2((float)(pl1*wq), h, l2); PWh[pwB + (m+1)*256 + k] = h; PWl[pwB + (m+1)*256 + k] = l2;
    for (int l = m + 2; l < 128; ++l) {
      const double dl = (double)l, dm = (double)m;
      const double a = sqrt((4.0*dl*dl - 1.0) / (dl*dl - dm*dm));
      const double b = sqrt(((dl-1.0)*(dl-1.0) - dm*dm) / (4.0*(dl-1.0)*(dl-1.0) - 1.0));
      const double pl = a * (ct * pl1 - b * pl2v);
      split2((float)pl, h, l2);      PTh[ptB + l] = h; PTl[ptB + l] = l2;
      split2((float)(pl*wq), h, l2); PWh[pwB + l*256 + k] = h; PWl[pwB + l*256 + k] = l2;
      pl2v = pl1; pl1 = pl;
    }
  }
}

// ---------------- split-bf16 MFMA GEMM ----------------
// C[i][j] = sum_k A[i][k]*B[j][k]. Block 128x128, 4 waves (64x64 each), BK=32.
// AM: 0 = A from pre-split bf16 [i][k]; 2 = A from fp32 [k][i] (transpose+cvt).
// BM: 0 = B from pre-split bf16 [j][k]; 1 = B from fp32 [j][k] (cvt).
// LDS pitch 40 shorts (80 B): 16B-aligned rows, ~2-way bank aliasing (free).
template<int AM, int BM>
__global__ __launch_bounds__(256) void mfma_gemm(
    const ushort* __restrict__ Ah, const ushort* __restrict__ Al, const float* __restrict__ Af,
    const ushort* __restrict__ Bh, const ushort* __restrict__ Bl, const float* __restrict__ Bf,
    float* __restrict__ C,
    int lda, int ldb, int ldc, int K,
    long aZ, int aShift, long bZ, int bShift, long cZ, int cColOff, int kFromZ)
{
  __shared__ __align__(16) short sAh[128*40];
  __shared__ __align__(16) short sAl[128*40];
  __shared__ __align__(16) short sBh[128*40];
  __shared__ __align__(16) short sBl[128*40];
  const int z = blockIdx.z;
  const long aOff = ((long)(z >> aShift)) * aZ;
  const long bOff = ((long)(z >> bShift)) * bZ;
  const long cOff = (long)z * cZ;
  const int i0 = blockIdx.y * 128;
  const int j0 = blockIdx.x * 128;
  const int t = threadIdx.x;
  const int lane = t & 63, w = t >> 6;
  const int wy = w >> 1, wx = w & 1;
  const int il = lane & 15, q = lane >> 4;
  const int kstart = kFromZ ? ((z >> 1) & ~31) : 0;

  f32x4 acc[4][4];
#pragma unroll
  for (int a = 0; a < 4; ++a)
#pragma unroll
    for (int b = 0; b < 4; ++b) acc[a][b] = (f32x4){0.f, 0.f, 0.f, 0.f};

  for (int k0 = kstart; k0 < K; k0 += 32) {
    __syncthreads();
    // ---- stage A ----
    if constexpr (AM == 0) {
      const int r = t >> 1, ks = (t & 1) * 16;
      const size_t g = (size_t)aOff + (size_t)(i0 + r) * lda + k0 + ks;
      *(short8*)&sAh[r*40+ks]   = *(const short8*)(Ah + g);
      *(short8*)&sAh[r*40+ks+8] = *(const short8*)(Ah + g + 8);
      *(short8*)&sAl[r*40+ks]   = *(const short8*)(Al + g);
      *(short8*)&sAl[r*40+ks+8] = *(const short8*)(Al + g + 8);
    } else {  // AM == 2: fp32 [k][i] -> transpose + split
      const int kk0 = 8*w + 2*q;               // even, 0..30
      const float* s0 = Af + aOff + (size_t)(k0 + kk0) * lda + i0 + il;
      const float* s1 = s0 + lda;
#pragma unroll
      for (int c = 0; c < 8; ++c) {
        float v0 = s0[c*16], v1 = s1[c*16];
        ushort h0,l0,h1,l1; split2(v0,h0,l0); split2(v1,h1,l1);
        const int idx = (il + 16*c)*40 + kk0;
        *(uint*)&sAh[idx] = (uint)h0 | ((uint)h1 << 16);
        *(uint*)&sAl[idx] = (uint)l0 | ((uint)l1 << 16);
      }
    }
    // ---- stage B ----
    if constexpr (BM == 0) {
      const int r = t >> 1, ks = (t & 1) * 16;
      const size_t g = (size_t)bOff + (size_t)(j0 + r) * ldb + k0 + ks;
      *(short8*)&sBh[r*40+ks]   = *(const short8*)(Bh + g);
      *(short8*)&sBh[r*40+ks+8] = *(const short8*)(Bh + g + 8);
      *(short8*)&sBl[r*40+ks]   = *(const short8*)(Bl + g);
      *(short8*)&sBl[r*40+ks+8] = *(const short8*)(Bl + g + 8);
    } else {  // BM == 1: fp32 [j][k] -> split
      const int r = t >> 1, ks = (t & 1) * 16;
      const float* src = Bf + bOff + (size_t)(j0 + r) * ldb + k0 + ks;
#pragma unroll
      for (int jj = 0; jj < 4; ++jj) {
        float4 f = *(const float4*)(src + 4*jj);
        ushort h0,l0,h1,l1,h2,l2,h3,l3;
        split2(f.x,h0,l0); split2(f.y,h1,l1); split2(f.z,h2,l2); split2(f.w,h3,l3);
        *(ushort4*)&sBh[r*40+ks+4*jj] = make_ushort4(h0,h1,h2,h3);
        *(ushort4*)&sBl[r*40+ks+4*jj] = make_ushort4(l0,l1,l2,l3);
      }
    }
    __syncthreads();
    // ---- compute: 16 tiles x 3 split-MFMAs ----
    short8 afh[4], afl[4];
#pragma unroll
    for (int mi = 0; mi < 4; ++mi) {
      const int row = wy*64 + mi*16 + il;
      afh[mi] = *(const short8*)&sAh[row*40 + q*8];
      afl[mi] = *(const short8*)&sAl[row*40 + q*8];
    }
#pragma unroll
    for (int nj = 0; nj < 4; ++nj) {
      const int row = wx*64 + nj*16 + il;
      short8 bfh = *(const short8*)&sBh[row*40 + q*8];
      short8 bfl = *(const short8*)&sBl[row*40 + q*8];
#pragma unroll
      for (int mi = 0; mi < 4; ++mi) {
        acc[mi][nj] = __builtin_amdgcn_mfma_f32_16x16x32_bf16(afh[mi], bfh, acc[mi][nj], 0, 0, 0);
        acc[mi][nj] = __builtin_amdgcn_mfma_f32_16x16x32_bf16(afh[mi], bfl, acc[mi][nj], 0, 0, 0);
        acc[mi][nj] = __builtin_amdgcn_mfma_f32_16x16x32_bf16(afl[mi], bfh, acc[mi][nj], 0, 0, 0);
      }
    }
  }
  // ---- epilogue: D col = lane&15 (N), row = q*4+r (M) ----
#pragma unroll
  for (int mi = 0; mi < 4; ++mi)
#pragma unroll
    for (int nj = 0; nj < 4; ++nj)
#pragma unroll
      for (int r = 0; r < 4; ++r) {
        const long gi = i0 + wy*64 + mi*16 + q*4 + r;
        const long gj = j0 + wx*64 + nj*16 + il;
        C[cOff + gi*ldc + cColOff + gj] = acc[mi][nj][r];
      }
}

// ---------------- K3: per-coefficient channel mixing (fp32, unchanged) -------
__global__ __launch_bounds__(256) void k_stagec(const float* __restrict__ spec,
                                                const float* __restrict__ w,
                                                float* __restrict__ outb) {
  const int cb = blockIdx.x, l = blockIdx.y;
  if (cb * 16 > l) return;
  __shared__ float s_spec[32 * 257];
  __shared__ float s_w[256 * 33];
  const int t = threadIdx.x;
  const int c = t & 31, og = t >> 5;
  const size_t x0 = 258u * l + cb * 32;
  for (int cc = 0; cc < 32; ++cc)
    s_spec[cc * 257 + t] = spec[(size_t)(cb * 32 + cc) * 32768 + l * 256 + t];
  float acc[8][4] = {{0.f}};
  const int lr = t >> 4;
  const int lq = (t & 15) * 2;
  for (int isub = 0; isub < 4; ++isub) {
    __syncthreads();
    for (int pass = 0; pass < 16; ++pass) {
      const int rho = pass * 16 + lr;
      const int io = (isub * 8 + (rho >> 5)) * 32 + (rho & 31);
      const float2 wv = *(const float2*)&w[(size_t)io * 33024 + x0 + lq];
      s_w[rho * 33 + lq]     = wv.x;
      s_w[rho * 33 + lq + 1] = wv.y;
    }
    __syncthreads();
#pragma unroll
    for (int idp = 0; idp < 4; ++idp) {
      const int i0 = isub * 8 + idp * 2;
      const int r0 = idp * 64;
      float2 sv[8];
#pragma unroll
      for (int b = 0; b < 8; ++b)
        sv[b] = *(const float2*)&s_spec[c * 257 + b * 32 + i0];
      float wv0[4], wv1[4];
#pragma unroll
      for (int od = 0; od < 4; ++od) {
        wv0[od] = s_w[(r0 + og * 4 + od) * 33 + c];
        wv1[od] = s_w[(r0 + 32 + og * 4 + od) * 33 + c];
      }
#pragma unroll
      for (int b = 0; b < 8; ++b)
#pragma unroll
        for (int od = 0; od < 4; ++od)
          acc[b][od] = fmaf(sv[b].x, wv0[od], fmaf(sv[b].y, wv1[od], acc[b][od]));
    }
  }
  __syncthreads();
#pragma unroll
  for (int b = 0; b < 8; ++b)
#pragma unroll
    for (int od = 0; od < 4; ++od)
      s_w[c * 257 + b * 32 + og * 4 + od] = acc[b][od];
  __syncthreads();
  for (int cc = 0; cc < 32; ++cc)
    outb[(size_t)(cb * 32 + cc) * 32768 + l * 256 + t] = s_w[cc * 257 + t];
}

// ---------------- launch ----------------
extern "C" void kernel_launch(void* const* d_in, const int* in_sizes, int n_in,
                              void* d_out, int out_size, void* d_ws, size_t ws_size,
                              hipStream_t stream) {
  const float* x = (const float*)d_in[0];   // (8,32,256,256)
  const float* w = (const float*)d_in[1];   // (32,32,33024)
  float* y = (float*)d_out;                 // (8,32,256,256)
  char* ws = (char*)d_ws;

  // workspace layout (bytes); total = 168,296,448 (same as validated R2 size)
  ushort* Th   = (ushort*)(ws + 0);          //  256*256 bf16
  ushort* Tl   = (ushort*)(ws + 131072);
  ushort* TiTh = (ushort*)(ws + 262144);     //  [n][mc]
  ushort* TiTl = (ushort*)(ws + 393216);
  ushort* PWh  = (ushort*)(ws + 524288);     //  [m][l][k]  8 MB
  ushort* PWl  = (ushort*)(ws + 8912896);
  ushort* PTh  = (ushort*)(ws + 17301504);   //  [m][k][l]  8 MB
  ushort* PTl  = (ushort*)(ws + 25690112);
  float* XHhalf= (float*)(ws + 34078720);    //  256 x 32768 fp32 (33.5 MB); outb overlays
  float* outb  = XHhalf;
  float* spec  = (float*)(ws + 67633152);    //  [mc][l][bc] fp32 (33.5 MB)
  float* XM    = (float*)(ws + 101187584);   //  [mc][bo*256+k] fp32 (67 MB)

  // K0: tables
  k_tables<<<dim3(129), dim3(256), 0, stream>>>(Th, Tl, TiTh, TiTl, PWh, PWl, PTh, PTl);

  for (int half = 0; half < 2; ++half) {
    // K1: fwd DFT  XHhalf[mc][row] = sum_n T[mc][n] * x[rowg][n]; M=256, N=32768, K=256
    mfma_gemm<0,1><<<dim3(256, 2, 1), dim3(256), 0, stream>>>(
        Th, Tl, nullptr, nullptr, nullptr, x + (size_t)half * 8388608, XHhalf,
        256, 256, 32768, 256, 0L, 0, 0L, 0, 0L, 0, 0);
    // K2: fwd Legendre per z=mc: spec[z][l][bc] = sum_k PW[m][l][k]*XHhalf[z][bc][k]
    mfma_gemm<0,1><<<dim3(1, 1, 256), dim3(256), 0, stream>>>(
        PWh, PWl, nullptr, nullptr, nullptr, XHhalf, spec,
        256, 256, 256, 256, 32768L, 1, 32768L, 0, 32768L, half * 128, 0);
  }

  // K3: channel mixing (fp32)
  k_stagec<<<dim3(8, 128), dim3(256), 0, stream>>>(spec, w, outb);

  // K4: inv Legendre per z=mc: XM[z][bo*256+kl] = sum_l outb[z][l][bo]*PT[m][kl][l]
  mfma_gemm<2,0><<<dim3(2, 2, 256), dim3(256), 0, stream>>>(
      nullptr, nullptr, outb, PTh, PTl, nullptr, XM,
      256, 128, 256, 128, 32768L, 0, 32768L, 1, 65536L, 0, 1);

  // K5: inv DFT: y[row][n] = sum_mc XM[mc][row]*TiT[n][mc]
  mfma_gemm<2,0><<<dim3(2, 512, 1), dim3(256), 0, stream>>>(
      nullptr, nullptr, XM, TiTh, TiTl, nullptr, y,
      65536, 256, 256, 256, 0L, 0, 0L, 0, 0L, 0, 0);
}